// Round 18
// baseline (86.146 us; speedup 1.0000x reference)
//
#include <hip/hip_runtime.h>
#include <hip/hip_bf16.h>

#define NB   4
#define NROW 4096      // W*W
#define CIN  256
#define OUTC 512
#define DP   32
#define LOG2E 1.4426950408889634f

typedef __bf16 bf16x8 __attribute__((ext_vector_type(8)));
typedef float  f32x4  __attribute__((ext_vector_type(4)));
typedef float  f32x16 __attribute__((ext_vector_type(16)));
typedef ushort ushort8 __attribute__((ext_vector_type(8)));

#define MFMA32(a, b, c) __builtin_amdgcn_mfma_f32_32x32x16_bf16((a), (b), (c), 0, 0, 0)

__device__ __forceinline__ ushort f2bf(float x) {
  union { float f; unsigned u; } v; v.f = x;
  unsigned r = v.u + 0x7fffu + ((v.u >> 16) & 1u);   // RNE
  return (ushort)(r >> 16);
}

__device__ __forceinline__ uint pack2(float a, float b) {
  __hip_bfloat162 h = __float22bfloat162_rn(float2{a, b});  // v_cvt_pk_bf16_f32
  uint u; __builtin_memcpy(&u, &h, 4);
  return u;
}

__device__ __forceinline__ bf16x8 mk8(uint a, uint b, uint c, uint d) {
  uint tmp[4] = {a, b, c, d};
  bf16x8 r; __builtin_memcpy(&r, tmp, 16);
  return r;
}

// Raw 2^x via the compiler intrinsic: single v_exp_f32, hazard-safe
// (r13's inline-asm variant hit the TRANS wait-state hazard).
__device__ __forceinline__ float fexp2(float x) {
  return __builtin_amdgcn_exp2f(x);
}

__device__ __forceinline__ void gload_lds16(const void* g, void* l) {
  __builtin_amdgcn_global_load_lds(
      (const __attribute__((address_space(1))) unsigned int*)g,
      (__attribute__((address_space(3))) unsigned int*)l, 16, 0, 0);
}

// ===========================================================================
// SPLIT-K PATH
// ===========================================================================

// MFMA projection: block = 64 rows. which==0: g = x@g_w -> Qb (log2e-scaled)
// + concat-copy x into out[...,256:512]. which==1: f = h@f_w -> Kb, plus V in
// the PV-ready layout (r8-proven):
//   Vw tile image (16384 ushorts per (b,tile)) = [kt][c][s2][8]:
//   keys 16kt + 8*(s2 ^ (c&1)) + j of channel c.
__global__ __launch_bounds__(256) void proj_mfma(
    const float* __restrict__ x, const float* __restrict__ h,
    const float* __restrict__ fw, const float* __restrict__ gw,
    ushort* __restrict__ Qb, ushort* __restrict__ Kb, ushort* __restrict__ Vw,
    float* __restrict__ out) {
  __shared__ ushort Ab[64 * 256];   // 32KB swizzled rows
  __shared__ ushort Wt[32 * 256];   // 16KB W^T [d][k] linear
  const int t = threadIdx.x;
  const int which = blockIdx.y;
  const float* in   = which ? h : x;
  const float* wsrc = which ? fw : gw;
  ushort* dst = which ? Kb : Qb;
  const float qsc = which ? 1.f : LOG2E;
  const int row0 = blockIdx.x * 64;

  {  // stage A: coalesced float4 reads, 8B swizzled LDS writes (+ concat)
    const float4* inp = (const float4*)(in + (size_t)row0 * CIN);
#pragma unroll
    for (int i = 0; i < 16; ++i) {
      const int idx = i * 256 + t;
      const int r = idx >> 6;
      const int c = (idx & 63) * 4;
      const float4 v = inp[idx];
      if (!which)   // out[...,256:512] = x  (concat fused here)
        ((float4*)(out + (size_t)(row0 + r) * OUTC + 256))[idx & 63] = v;
      ushort tmp[4] = {f2bf(v.x), f2bf(v.y), f2bf(v.z), f2bf(v.w)};
      const int slot = (c >> 3) ^ (r & 7);
      *(uint2*)&Ab[r * 256 + (slot << 3) + (c & 7)] = *(const uint2*)tmp;
    }
  }
  {  // stage W^T (tiny, L2-hot)
    const int d = t & 31;
    const int k0 = (t >> 5) * 32;
#pragma unroll 8
    for (int j = 0; j < 32; ++j)
      Wt[d * 256 + k0 + j] = f2bf(wsrc[(size_t)(k0 + j) * DP + d]);
  }
  __syncthreads();

  const int w = t >> 6, l = t & 63, lo = l & 15, hi = l >> 4;
  f32x4 acc[2];
  acc[0] = (f32x4){0.f, 0.f, 0.f, 0.f};
  acc[1] = (f32x4){0.f, 0.f, 0.f, 0.f};
  const int R = w * 16 + lo;          // A-row this lane supplies
#pragma unroll
  for (int kk = 0; kk < 8; ++kk) {
    const int slot = (kk * 4 + hi) ^ (R & 7);
    const bf16x8 a = *(const bf16x8*)&Ab[R * 256 + (slot << 3)];
#pragma unroll
    for (int nt = 0; nt < 2; ++nt) {
      const bf16x8 bfr = *(const bf16x8*)&Wt[(nt * 16 + lo) * 256 + kk * 32 + hi * 8];
      acc[nt] = __builtin_amdgcn_mfma_f32_16x16x32_bf16(a, bfr, acc[nt], 0, 0, 0);
    }
  }
  // D: row = 4*hi + r (projected row), col = lo (output channel)
#pragma unroll
  for (int nt = 0; nt < 2; ++nt)
#pragma unroll
    for (int r = 0; r < 4; ++r)
      dst[(size_t)(row0 + w * 16 + hi * 4 + r) * DP + nt * 16 + lo] =
          f2bf(acc[nt][r] * qsc);

  if (which) {  // V: column-gather from swizzled Ab into [kt][c][s2] image
    const int b = row0 >> 12;
    const int tile = (row0 & 4095) >> 6;
    const int c = t;
    ushort* vdst = Vw + (size_t)(b * 64 + tile) * 16384;
#pragma unroll
    for (int kt = 0; kt < 4; ++kt)
#pragma unroll
      for (int s2 = 0; s2 < 2; ++s2) {
        const int kbase = 16 * kt + 8 * (s2 ^ (c & 1));
        ushort tmp[8];
#pragma unroll
        for (int j = 0; j < 8; ++j) {
          const int slot = (c >> 3) ^ j;     // key row = kbase+j -> row&7 = j
          tmp[j] = Ab[(kbase + j) * 256 + (slot << 3) + (c & 7)];
        }
        *(ushort8*)(vdst + kt * 4096 + c * 16 + s2 * 8) = *(const ushort8*)tmp;
      }
  }
}

// Flash attention, OCCUPANCY-3 variant: block = 4 waves, wave = 32 q x 128 ch
// ((qs,chh) = (w&1, w>>1)); acc = 4 x f32x16 = 64 AGPR -> 3 waves/SIMD.
// Wave-pairs duplicate QK+softmax (cheap post-no-max: ~60 VALU/tile).
// Single-buffered 32KB Vt, 2 barriers/tile (r2-proven schedule): stage(t+1)
// issued after the read-done barrier, drains under next tile's QK+softmax.
// NO-MAX softmax, P in registers, raw v_exp_f32, r14 weave preserved.
// Fragment layouts (32x32x16 bf16): A row=l&31,k=8*(l>>5)+j ;
// B col=l&31,k=8*(l>>5)+j ; D col=l&31,row=(reg&3)+8*(reg>>2)+4*(l>>5).
__global__ __launch_bounds__(256, 3) void attn64c(
    const ushort* __restrict__ Qb, const ushort* __restrict__ Kb,
    const ushort* __restrict__ Vw, float* __restrict__ pml,
    ushort* __restrict__ pacc) {
  __shared__ ushort Vt[16384];   // 32KB single-buffered [kt][c][s2] image

  const int t  = threadIdx.x;
  const int w  = t >> 6;
  const int l  = t & 63;
  const int qq = l & 31;
  const int h  = l >> 5;
  const int qs  = w & 1;
  const int chh = w >> 1;

  const int bid = blockIdx.x;      // bid&15 = (b,s): same-V blocks share an XCD
  const int s   = bid & 3;
  const int b   = (bid >> 2) & 3;
  const int q0  = (bid >> 4) * 64 + qs * 32;
  const size_t rbase = (size_t)b * NROW;

  // Q as B-operand: col=q=qq, k = ks*16 + 8h + j  (log2e-scaled at proj)
  bf16x8 qf0 = *(const bf16x8*)(Qb + (rbase + q0 + qq) * DP + h * 8);
  bf16x8 qf1 = *(const bf16x8*)(Qb + (rbase + q0 + qq) * DP + 16 + h * 8);

  f32x16 acc[4];
#pragma unroll
  for (int i = 0; i < 4; ++i) acc[i] = (f32x16){};
  float lsum = 0.f;

  const int tI0 = s * 16;
  // per-lane LDS byte base: c = chh*128 + ct*32 + qq -> chh*4096 + qq*32;
  // slot = (h ^ (c&1))*16 with c&1 == qq&1.
  const int vlane = chh * 4096 + qq * 32 + ((h ^ (qq & 1)) << 4);

  // lane-constant K offsets (ushort units); pointers step by constant strides
  const int ko00 = qq * DP + h * 8;
  const int ko01 = qq * DP + 16 + h * 8;
  const int ko10 = (32 + qq) * DP + h * 8;
  const int ko11 = (32 + qq) * DP + 16 + h * 8;
  const ushort* kfp  = Kb + (rbase + (size_t)(tI0 + 1) * 64) * DP;  // next tile
  const ushort* vsrc = Vw + (size_t)(b * 64 + tI0 + 1) * 16384;     // next tile

  // prologue: stage V tile 0, load K fragments for tile 0, drain
  {
    const ushort* src0 = Vw + (size_t)(b * 64 + tI0) * 16384;
#pragma unroll
    for (int i = 0; i < 8; ++i)
      gload_lds16(src0 + (w * 8 + i) * 512 + l * 8, &Vt[(w * 8 + i) * 512]);
  }
  bf16x8 kf00, kf01, kf10, kf11;
  {
    const ushort* k0 = Kb + (rbase + (size_t)tI0 * 64) * DP;
    kf00 = *(const bf16x8*)(k0 + ko00);
    kf01 = *(const bf16x8*)(k0 + ko01);
    kf10 = *(const bf16x8*)(k0 + ko10);
    kf11 = *(const bf16x8*)(k0 + ko11);
  }
  __syncthreads();

  for (int tt = 0; tt < 16; ++tt) {
    // S^T = K Q^T (log2 domain) — register-only, runs while stage(tt) lands
    f32x16 st0 = (f32x16){}, st1 = (f32x16){};
    st0 = MFMA32(kf00, qf0, st0);
    st0 = MFMA32(kf01, qf1, st0);
    st1 = MFMA32(kf10, qf0, st1);
    st1 = MFMA32(kf11, qf1, st1);

    // half-0 softmax: exp2 + sum + pack pb0/pb1 (hides under QK tail + stage)
#pragma unroll
    for (int i = 0; i < 16; ++i) st0[i] = fexp2(st0[i]);
    float s0;
    {
      float sm[8];
#pragma unroll
      for (int i = 0; i < 8; ++i) sm[i] = st0[i] + st0[i + 8];
#pragma unroll
      for (int d = 4; d >= 1; d >>= 1)
#pragma unroll
        for (int i = 0; i < d; ++i) sm[i] += sm[i + d];
      s0 = sm[0];
    }
    bf16x8 pb0, pb1;
    {
      const uint a00 = pack2(st0[0],  st0[1]),  a01 = pack2(st0[2],  st0[3]);
      const uint a10 = pack2(st0[4],  st0[5]),  a11 = pack2(st0[6],  st0[7]);
      const uint a20 = pack2(st0[8],  st0[9]),  a21 = pack2(st0[10], st0[11]);
      const uint a30 = pack2(st0[12], st0[13]), a31 = pack2(st0[14], st0[15]);
      auto p0 = __builtin_amdgcn_permlane32_swap(a00, a10, false, false);
      auto p1 = __builtin_amdgcn_permlane32_swap(a01, a11, false, false);
      auto p2 = __builtin_amdgcn_permlane32_swap(a20, a30, false, false);
      auto p3 = __builtin_amdgcn_permlane32_swap(a21, a31, false, false);
      pb0 = mk8(p0[0], p1[0], p0[1], p1[1]);
      pb1 = mk8(p2[0], p3[0], p2[1], p3[1]);
    }

    __syncthreads();   // drains vmcnt: Vt(tt) staged + visible

    const char* vb = (const char*)&Vt[0] + vlane;
    __builtin_amdgcn_s_setprio(1);
    // PV half-0 (kt 0,1) with exp2(st1) woven between MFMAs
#pragma unroll
    for (int ct = 0; ct < 4; ++ct) {
      const bf16x8 v0 = *(const bf16x8*)(vb + ct * 1024);
      const bf16x8 v1 = *(const bf16x8*)(vb + 8192 + ct * 1024);
      acc[ct] = MFMA32(v0, pb0, acc[ct]);
      st1[4 * ct]     = fexp2(st1[4 * ct]);
      st1[4 * ct + 1] = fexp2(st1[4 * ct + 1]);
      acc[ct] = MFMA32(v1, pb1, acc[ct]);
      st1[4 * ct + 2] = fexp2(st1[4 * ct + 2]);
      st1[4 * ct + 3] = fexp2(st1[4 * ct + 3]);
    }
    // pack pb2/pb3
    bf16x8 pb2, pb3;
    {
      const uint b00 = pack2(st1[0],  st1[1]),  b01 = pack2(st1[2],  st1[3]);
      const uint b10 = pack2(st1[4],  st1[5]),  b11 = pack2(st1[6],  st1[7]);
      const uint b20 = pack2(st1[8],  st1[9]),  b21 = pack2(st1[10], st1[11]);
      const uint b30 = pack2(st1[12], st1[13]), b31 = pack2(st1[14], st1[15]);
      auto p4 = __builtin_amdgcn_permlane32_swap(b00, b10, false, false);
      auto p5 = __builtin_amdgcn_permlane32_swap(b01, b11, false, false);
      auto p6 = __builtin_amdgcn_permlane32_swap(b20, b30, false, false);
      auto p7 = __builtin_amdgcn_permlane32_swap(b21, b31, false, false);
      pb2 = mk8(p4[0], p5[0], p4[1], p5[1]);
      pb3 = mk8(p6[0], p7[0], p6[1], p7[1]);
    }

    // PV half-1 (kt 2,3) with K-prefetch + st1 row-sum woven between MFMAs.
    // (kf prefetch reads one tile past K range at tt==15 — lands in Vw region
    //  of the same workspace allocation; values unused.)
    float s1 = 0.f;
#pragma unroll
    for (int ct = 0; ct < 4; ++ct) {
      const bf16x8 v2 = *(const bf16x8*)(vb + 16384 + ct * 1024);
      const bf16x8 v3 = *(const bf16x8*)(vb + 24576 + ct * 1024);
      acc[ct] = MFMA32(v2, pb2, acc[ct]);
      if (ct == 0) kf00 = *(const bf16x8*)(kfp + ko00);
      if (ct == 1) kf01 = *(const bf16x8*)(kfp + ko01);
      if (ct == 2) kf10 = *(const bf16x8*)(kfp + ko10);
      if (ct == 3) kf11 = *(const bf16x8*)(kfp + ko11);
      acc[ct] = MFMA32(v3, pb3, acc[ct]);
      s1 += (st1[4 * ct] + st1[4 * ct + 1]) + (st1[4 * ct + 2] + st1[4 * ct + 3]);
    }
    __builtin_amdgcn_s_setprio(0);
    lsum += s0 + s1;

    __syncthreads();   // all waves done reading Vt(tt)

    if (tt < 15) {     // stage next tile; drains under next iter's QK+softmax
#pragma unroll
      for (int i = 0; i < 8; ++i)
        gload_lds16(vsrc + (w * 8 + i) * 512 + l * 8, &Vt[(w * 8 + i) * 512]);
    }
    kfp += 64 * DP;    // SALU pointer step
    vsrc += 16384;     // SALU pointer step
  }

  // epilogue: finish row sum, store partials (chh halves hold identical lsum)
  lsum += __shfl_xor(lsum, 32, 64);
  const size_t prow = rbase + q0 + qq;
  if (h == 0 && chh == 0) pml[prow * 4 + s] = lsum;
  // pacc bf16 [row][s][256]; channel = chh*128 + ct*32 + 8j + 4h + {0..3}
  ushort* pr = pacc + (prow * 4 + s) * 256 + chh * 128;
#pragma unroll
  for (int ct = 0; ct < 4; ++ct)
#pragma unroll
    for (int j = 0; j < 4; ++j) {
      uint2 d;
      d.x = pack2(acc[ct][4 * j], acc[ct][4 * j + 1]);
      d.y = pack2(acc[ct][4 * j + 2], acc[ct][4 * j + 3]);
      *(uint2*)&pr[ct * 32 + j * 8 + h * 4] = d;
    }
}

// Combine partials (plain sums — no-max softmax) -> out[...,0:256].
__global__ __launch_bounds__(256) void reduce_o(
    const float* __restrict__ pml, const ushort* __restrict__ pacc,
    float* __restrict__ out) {
  const int t = threadIdx.x;
  const int row = blockIdx.x * 8 + (t >> 5);
  const int c0 = (t & 31) * 8;

  const float L = pml[row * 4] + pml[row * 4 + 1] + pml[row * 4 + 2] + pml[row * 4 + 3];
  float o[8] = {0.f, 0.f, 0.f, 0.f, 0.f, 0.f, 0.f, 0.f};
#pragma unroll
  for (int s = 0; s < 4; ++s) {
    const bf16x8 a = *(const bf16x8*)(pacc + ((size_t)row * 4 + s) * 256 + c0);
#pragma unroll
    for (int i = 0; i < 8; ++i) o[i] += (float)a[i];
  }
  const float inv = 1.f / L;
  float4 o0 = {o[0] * inv, o[1] * inv, o[2] * inv, o[3] * inv};
  float4 o1 = {o[4] * inv, o[5] * inv, o[6] * inv, o[7] * inv};
  float4* op = (float4*)(out + (size_t)row * OUTC + c0);
  op[0] = o0; op[1] = o1;
}

// ===========================================================================
// FALLBACK PATH (round-1, no workspace) — used only if ws_size too small
// ===========================================================================
__global__ __launch_bounds__(256) void proj_fb(
    const float* __restrict__ x, const float* __restrict__ h,
    const float* __restrict__ fw, const float* __restrict__ gw,
    float* __restrict__ out) {
  __shared__ float wl[8192];
  __shared__ float rows[8][260];
  const int t = threadIdx.x;
  const int which = blockIdx.y;
  const float* in = which ? h : x;
  const float* w  = which ? fw : gw;
  for (int i = t; i < 8192; i += 256) wl[i] = w[i];
  const int row0 = blockIdx.x * 32;
  const int d = t & 31, rl = t >> 5;
  for (int rp = 0; rp < 4; ++rp) {
    __syncthreads();
    for (int i = t; i < 2048; i += 256)
      rows[i >> 8][i & 255] = in[(long)(row0 + rp * 8 + (i >> 8)) * CIN + (i & 255)];
    __syncthreads();
    float a = 0.f;
#pragma unroll 8
    for (int c = 0; c < 256; ++c) a = fmaf(rows[rl][c], wl[c * 32 + d], a);
    const long row = row0 + rp * 8 + rl;
    ((ushort*)(out + row * OUTC + 256))[which * 32 + d] = f2bf(a);
  }
}

__global__ __launch_bounds__(256) void attn_fb(
    const float* __restrict__ h, float* __restrict__ out) {
  __shared__ alignas(16) ushort Vt[256][72];
  __shared__ alignas(16) ushort Pl[4][16][72];
  const int t = threadIdx.x;
  const int w = t >> 6, l = t & 63, lo = l & 15, hi = l >> 4;
  const int bid = blockIdx.x;
  const int b = (bid >> 1) & 3;
  const int qb = ((bid >> 3) << 1) | (bid & 1);
  const int q0 = qb * 64;
  const long rowbase = (long)b * NROW;
  const ushort* gslot = (const ushort*)(out + (rowbase + q0 + w * 16 + lo) * OUTC + 256);
  const bf16x8 qf = *(const bf16x8*)(gslot + hi * 8);
  f32x4 acc[16];
#pragma unroll
  for (int i = 0; i < 16; ++i) acc[i] = (f32x4){0.f, 0.f, 0.f, 0.f};
  float mrow[4] = {-1e30f, -1e30f, -1e30f, -1e30f};
  float lsum[4] = {0.f, 0.f, 0.f, 0.f};
  for (int k0 = 0; k0 < NROW; k0 += 64) {
    bf16x8 kf[4];
#pragma unroll
    for (int kt = 0; kt < 4; ++kt) {
      const ushort* fslot =
          (const ushort*)(out + (rowbase + k0 + kt * 16 + lo) * OUTC + 256) + 32;
      kf[kt] = *(const bf16x8*)(fslot + hi * 8);
    }
    __syncthreads();
    {
      const float* hp = h + (rowbase + k0) * CIN + t;
#pragma unroll
      for (int g8 = 0; g8 < 8; ++g8) {
        ushort tmp[8];
#pragma unroll
        for (int i = 0; i < 8; ++i) tmp[i] = f2bf(hp[(g8 * 8 + i) * CIN]);
        *(bf16x8*)&Vt[t][g8 * 8] = *(const bf16x8*)tmp;
      }
    }
    __syncthreads();
    f32x4 sv[4];
#pragma unroll
    for (int kt = 0; kt < 4; ++kt)
      sv[kt] = __builtin_amdgcn_mfma_f32_16x16x32_bf16(
          qf, kf[kt], (f32x4){0.f, 0.f, 0.f, 0.f}, 0, 0, 0);
    float alpha[4];
    bool upd = false;
#pragma unroll
    for (int r = 0; r < 4; ++r) {
      float m4 = fmaxf(fmaxf(sv[0][r], sv[1][r]), fmaxf(sv[2][r], sv[3][r]));
#pragma unroll
      for (int off = 1; off < 16; off <<= 1) m4 = fmaxf(m4, __shfl_xor(m4, off, 64));
      const float mn = fmaxf(mrow[r], m4);
      alpha[r] = __expf(mrow[r] - mn);
      upd |= (mn > mrow[r]);
      mrow[r] = mn;
    }
    if (__any(upd)) {
#pragma unroll
      for (int ct = 0; ct < 16; ++ct)
#pragma unroll
        for (int r = 0; r < 4; ++r) acc[ct][r] *= alpha[r];
#pragma unroll
      for (int r = 0; r < 4; ++r) lsum[r] *= alpha[r];
    }
#pragma unroll
    for (int r = 0; r < 4; ++r) {
      float ps = 0.f;
#pragma unroll
      for (int kt = 0; kt < 4; ++kt) {
        const float p = __expf(sv[kt][r] - mrow[r]);
        sv[kt][r] = p;
        ps += p;
      }
#pragma unroll
      for (int off = 1; off < 16; off <<= 1) ps += __shfl_xor(ps, off, 64);
      lsum[r] += ps;
    }
#pragma unroll
    for (int kt = 0; kt < 4; ++kt)
#pragma unroll
      for (int r = 0; r < 4; ++r)
        Pl[w][hi * 4 + r][kt * 16 + lo] = f2bf(sv[kt][r]);
    asm volatile("s_waitcnt lgkmcnt(0)" ::: "memory");
    const bf16x8 pa0 = *(const bf16x8*)&Pl[w][lo][hi * 8];
    const bf16x8 pa1 = *(const bf16x8*)&Pl[w][lo][32 + hi * 8];
#pragma unroll
    for (int ct = 0; ct < 16; ++ct) {
      const bf16x8 v0 = *(const bf16x8*)&Vt[ct * 16 + lo][hi * 8];
      const bf16x8 v1 = *(const bf16x8*)&Vt[ct * 16 + lo][32 + hi * 8];
      acc[ct] = __builtin_amdgcn_mfma_f32_16x16x32_bf16(pa0, v0, acc[ct], 0, 0, 0);
      acc[ct] = __builtin_amdgcn_mfma_f32_16x16x32_bf16(pa1, v1, acc[ct], 0, 0, 0);
    }
  }
#pragma unroll
  for (int r = 0; r < 4; ++r) {
    const float inv = 1.f / lsum[r];
    float* orow = out + (rowbase + q0 + w * 16 + hi * 4 + r) * OUTC;
#pragma unroll
    for (int ct = 0; ct < 16; ++ct) orow[ct * 16 + lo] = acc[ct][r] * inv;
  }
}

__global__ __launch_bounds__(256) void concat_fb(
    const float4* __restrict__ x, float4* __restrict__ out) {
  const int idx = blockIdx.x * 256 + threadIdx.x;
  const int row = idx >> 6, c4 = idx & 63;
  out[row * 128 + 64 + c4] = x[idx];
}

// ===========================================================================
extern "C" void kernel_launch(void* const* d_in, const int* in_sizes, int n_in,
                              void* d_out, int out_size, void* d_ws, size_t ws_size,
                              hipStream_t stream) {
  const float* x  = (const float*)d_in[0];
  const float* h  = (const float*)d_in[1];
  const float* fw = (const float*)d_in[2];
  const float* gw = (const float*)d_in[3];
  float* out = (float*)d_out;

  const size_t rows = (size_t)NB * NROW;                      // 16384
  const size_t base = 10ull * 1024 * 1024;                    // Q(1)+K(1)+V(8)
  const size_t need = base + rows * 4 * 8 + rows * 4 * 512;   // pml + pacc

  if (ws_size >= need) {
    ushort* Qw = (ushort*)d_ws;
    ushort* Kw = Qw + (1ull << 19);            // +1MB
    ushort* Vw = Kw + (1ull << 19);            // +1MB (V: 8MB)
    float*  pml  = (float*)((char*)d_ws + base);
    ushort* pacc = (ushort*)((char*)d_ws + base + rows * 4 * 8);

    proj_mfma<<<dim3(256, 2), 256, 0, stream>>>(x, h, fw, gw, Qw, Kw, Vw, out);
    attn64c<<<1024, 256, 0, stream>>>(Qw, Kw, Vw, pml, pacc);
    reduce_o<<<2048, 256, 0, stream>>>(pml, pacc, out);
  } else {
    proj_fb<<<dim3(512, 2), 256, 0, stream>>>(x, h, fw, gw, out);
    attn_fb<<<256, 256, 0, stream>>>(h, out);
    concat_fb<<<4096, 256, 0, stream>>>((const float4*)x, (float4*)out);
  }
}

// Round 19
// 73.184 us; speedup vs baseline: 1.1771x; 1.1771x over previous
//
#include <hip/hip_runtime.h>
#include <hip/hip_bf16.h>

#define NB   4
#define NROW 4096      // W*W
#define CIN  256
#define OUTC 512
#define DP   32
#define LOG2E 1.4426950408889634f

typedef __bf16 bf16x8 __attribute__((ext_vector_type(8)));
typedef float  f32x4  __attribute__((ext_vector_type(4)));
typedef float  f32x16 __attribute__((ext_vector_type(16)));
typedef ushort ushort8 __attribute__((ext_vector_type(8)));

#define MFMA32(a, b, c) __builtin_amdgcn_mfma_f32_32x32x16_bf16((a), (b), (c), 0, 0, 0)

__device__ __forceinline__ ushort f2bf(float x) {
  union { float f; unsigned u; } v; v.f = x;
  unsigned r = v.u + 0x7fffu + ((v.u >> 16) & 1u);   // RNE
  return (ushort)(r >> 16);
}

__device__ __forceinline__ uint pack2(float a, float b) {
  __hip_bfloat162 h = __float22bfloat162_rn(float2{a, b});  // v_cvt_pk_bf16_f32
  uint u; __builtin_memcpy(&u, &h, 4);
  return u;
}

__device__ __forceinline__ bf16x8 mk8(uint a, uint b, uint c, uint d) {
  uint tmp[4] = {a, b, c, d};
  bf16x8 r; __builtin_memcpy(&r, tmp, 16);
  return r;
}

// Raw 2^x via the compiler intrinsic: single v_exp_f32, hazard-safe
// (r13's inline-asm variant hit the TRANS wait-state hazard).
__device__ __forceinline__ float fexp2(float x) {
  return __builtin_amdgcn_exp2f(x);
}

__device__ __forceinline__ void gload_lds16(const void* g, void* l) {
  __builtin_amdgcn_global_load_lds(
      (const __attribute__((address_space(1))) unsigned int*)g,
      (__attribute__((address_space(3))) unsigned int*)l, 16, 0, 0);
}

// ===========================================================================
// SPLIT-K PATH
// ===========================================================================

// MFMA projection: block = 64 rows. which==0: g = x@g_w -> Qb (log2e-scaled)
// + concat-copy x into out[...,256:512]. which==1: f = h@f_w -> Kb, plus V in
// the PV-ready layout (r8-proven):
//   Vw tile image (16384 ushorts per (b,tile)) = [kt][c][s2][8]:
//   keys 16kt + 8*(s2 ^ (c&1)) + j of channel c.
__global__ __launch_bounds__(256) void proj_mfma(
    const float* __restrict__ x, const float* __restrict__ h,
    const float* __restrict__ fw, const float* __restrict__ gw,
    ushort* __restrict__ Qb, ushort* __restrict__ Kb, ushort* __restrict__ Vw,
    float* __restrict__ out) {
  __shared__ ushort Ab[64 * 256];   // 32KB swizzled rows
  __shared__ ushort Wt[32 * 256];   // 16KB W^T [d][k] linear
  const int t = threadIdx.x;
  const int which = blockIdx.y;
  const float* in   = which ? h : x;
  const float* wsrc = which ? fw : gw;
  ushort* dst = which ? Kb : Qb;
  const float qsc = which ? 1.f : LOG2E;
  const int row0 = blockIdx.x * 64;

  {  // stage A: coalesced float4 reads, 8B swizzled LDS writes (+ concat)
    const float4* inp = (const float4*)(in + (size_t)row0 * CIN);
#pragma unroll
    for (int i = 0; i < 16; ++i) {
      const int idx = i * 256 + t;
      const int r = idx >> 6;
      const int c = (idx & 63) * 4;
      const float4 v = inp[idx];
      if (!which)   // out[...,256:512] = x  (concat fused here)
        ((float4*)(out + (size_t)(row0 + r) * OUTC + 256))[idx & 63] = v;
      ushort tmp[4] = {f2bf(v.x), f2bf(v.y), f2bf(v.z), f2bf(v.w)};
      const int slot = (c >> 3) ^ (r & 7);
      *(uint2*)&Ab[r * 256 + (slot << 3) + (c & 7)] = *(const uint2*)tmp;
    }
  }
  {  // stage W^T (tiny, L2-hot)
    const int d = t & 31;
    const int k0 = (t >> 5) * 32;
#pragma unroll 8
    for (int j = 0; j < 32; ++j)
      Wt[d * 256 + k0 + j] = f2bf(wsrc[(size_t)(k0 + j) * DP + d]);
  }
  __syncthreads();

  const int w = t >> 6, l = t & 63, lo = l & 15, hi = l >> 4;
  f32x4 acc[2];
  acc[0] = (f32x4){0.f, 0.f, 0.f, 0.f};
  acc[1] = (f32x4){0.f, 0.f, 0.f, 0.f};
  const int R = w * 16 + lo;          // A-row this lane supplies
#pragma unroll
  for (int kk = 0; kk < 8; ++kk) {
    const int slot = (kk * 4 + hi) ^ (R & 7);
    const bf16x8 a = *(const bf16x8*)&Ab[R * 256 + (slot << 3)];
#pragma unroll
    for (int nt = 0; nt < 2; ++nt) {
      const bf16x8 bfr = *(const bf16x8*)&Wt[(nt * 16 + lo) * 256 + kk * 32 + hi * 8];
      acc[nt] = __builtin_amdgcn_mfma_f32_16x16x32_bf16(a, bfr, acc[nt], 0, 0, 0);
    }
  }
  // D: row = 4*hi + r (projected row), col = lo (output channel)
#pragma unroll
  for (int nt = 0; nt < 2; ++nt)
#pragma unroll
    for (int r = 0; r < 4; ++r)
      dst[(size_t)(row0 + w * 16 + hi * 4 + r) * DP + nt * 16 + lo] =
          f2bf(acc[nt][r] * qsc);

  if (which) {  // V: column-gather from swizzled Ab into [kt][c][s2] image
    const int b = row0 >> 12;
    const int tile = (row0 & 4095) >> 6;
    const int c = t;
    ushort* vdst = Vw + (size_t)(b * 64 + tile) * 16384;
#pragma unroll
    for (int kt = 0; kt < 4; ++kt)
#pragma unroll
      for (int s2 = 0; s2 < 2; ++s2) {
        const int kbase = 16 * kt + 8 * (s2 ^ (c & 1));
        ushort tmp[8];
#pragma unroll
        for (int j = 0; j < 8; ++j) {
          const int slot = (c >> 3) ^ j;     // key row = kbase+j -> row&7 = j
          tmp[j] = Ab[(kbase + j) * 256 + (slot << 3) + (c & 7)];
        }
        *(ushort8*)(vdst + kt * 4096 + c * 16 + s2 * 8) = *(const ushort8*)tmp;
      }
  }
}

// Flash attention, 32x32x16 MFMA, full 256 ch/wave, NO-MAX softmax
// (HW-validated r9/r10), P in registers, double-buffered Vt,
// immediate-offset V reads, and SOURCE-INTERLEAVED MFMA/VALU:
//   exp2(st1) woven into PV half-0; K-prefetch + row-sum woven into PV half-1.
// exp2 = __builtin_amdgcn_exp2f (bare v_exp_f32, hazard-safe).
// Fragment layouts (32x32x16 bf16): A row=l&31,k=8*(l>>5)+j ;
// B col=l&31,k=8*(l>>5)+j ; D col=l&31,row=(reg&3)+8*(reg>>2)+4*(l>>5).
// Swapped QK^T: st_e[reg] = S^T[key=e*32+(reg&3)+8*(reg>>2)+4h][q=l&31]
// Transposed PV:  acc[ct]  = O^T[c=ct*32+row][q=l&31]
__global__ __launch_bounds__(256, 2) void attn32f(
    const ushort* __restrict__ Qb, const ushort* __restrict__ Kb,
    const ushort* __restrict__ Vw, float* __restrict__ pml,
    ushort* __restrict__ pacc) {
  __shared__ ushort Vt[2][16384];   // 64KB double-buffered [kt][c][s2] image

  const int t  = threadIdx.x;
  const int w  = t >> 6;
  const int l  = t & 63;
  const int qq = l & 31;
  const int h  = l >> 5;

  const int bid = blockIdx.x;      // bid&15 = (b,s): same-V blocks share an XCD
  const int s   = bid & 3;
  const int b   = (bid >> 2) & 3;
  const int q0  = (bid >> 4) * 128 + w * 32;
  const size_t rbase = (size_t)b * NROW;

  // Q as B-operand: col=q=qq, k = ks*16 + 8h + j  (log2e-scaled at proj)
  bf16x8 qf0 = *(const bf16x8*)(Qb + (rbase + q0 + qq) * DP + h * 8);
  bf16x8 qf1 = *(const bf16x8*)(Qb + (rbase + q0 + qq) * DP + 16 + h * 8);

  f32x16 acc[8];
#pragma unroll
  for (int i = 0; i < 8; ++i) acc[i] = (f32x16){};
  float lsum = 0.f;

  const int tI0 = s * 16;
  // per-lane LDS read base (bytes): c-part qq*32 + slot (h^(qq&1))*16
  const int vlane = qq * 32 + ((h ^ (qq & 1)) << 4);

  // lane-constant K offsets (ushort units); pointers step by constant strides
  const int ko00 = qq * DP + h * 8;
  const int ko01 = qq * DP + 16 + h * 8;
  const int ko10 = (32 + qq) * DP + h * 8;
  const int ko11 = (32 + qq) * DP + 16 + h * 8;
  const ushort* kfp  = Kb + (rbase + (size_t)(tI0 + 1) * 64) * DP;  // next tile
  const ushort* vsrc = Vw + (size_t)(b * 64 + tI0 + 1) * 16384;     // next tile

  // prologue: stage V tile 0 into buf0, load K fragments for tile 0
  {
    const ushort* src0 = Vw + (size_t)(b * 64 + tI0) * 16384;
#pragma unroll
    for (int i = 0; i < 8; ++i)
      gload_lds16(src0 + (w * 8 + i) * 512 + l * 8, &Vt[0][(w * 8 + i) * 512]);
  }
  bf16x8 kf00, kf01, kf10, kf11;
  {
    const ushort* k0 = Kb + (rbase + (size_t)tI0 * 64) * DP;
    kf00 = *(const bf16x8*)(k0 + ko00);
    kf01 = *(const bf16x8*)(k0 + ko01);
    kf10 = *(const bf16x8*)(k0 + ko10);
    kf11 = *(const bf16x8*)(k0 + ko11);
  }
  __syncthreads();
  int cur = 0;

  for (int tt = 0; tt < 16; ++tt) {
    // stage NEXT tile into other buffer (drains at this iter's end barrier)
    if (tt < 15) {
      ushort* dstl = &Vt[cur ^ 1][0];
#pragma unroll
      for (int i = 0; i < 8; ++i)
        gload_lds16(vsrc + (w * 8 + i) * 512 + l * 8, dstl + (w * 8 + i) * 512);
    }

    // S^T = K Q^T (log2 domain)
    f32x16 st0 = (f32x16){}, st1 = (f32x16){};
    st0 = MFMA32(kf00, qf0, st0);
    st0 = MFMA32(kf01, qf1, st0);
    st1 = MFMA32(kf10, qf0, st1);
    st1 = MFMA32(kf11, qf1, st1);

    // half-0 softmax: exp2 + sum + pack pb0/pb1 (hides under QK tail)
#pragma unroll
    for (int i = 0; i < 16; ++i) st0[i] = fexp2(st0[i]);
    float s0;
    {
      float sm[8];
#pragma unroll
      for (int i = 0; i < 8; ++i) sm[i] = st0[i] + st0[i + 8];
#pragma unroll
      for (int d = 4; d >= 1; d >>= 1)
#pragma unroll
        for (int i = 0; i < d; ++i) sm[i] += sm[i + d];
      s0 = sm[0];
    }
    bf16x8 pb0, pb1;
    {
      const uint a00 = pack2(st0[0],  st0[1]),  a01 = pack2(st0[2],  st0[3]);
      const uint a10 = pack2(st0[4],  st0[5]),  a11 = pack2(st0[6],  st0[7]);
      const uint a20 = pack2(st0[8],  st0[9]),  a21 = pack2(st0[10], st0[11]);
      const uint a30 = pack2(st0[12], st0[13]), a31 = pack2(st0[14], st0[15]);
      auto p0 = __builtin_amdgcn_permlane32_swap(a00, a10, false, false);
      auto p1 = __builtin_amdgcn_permlane32_swap(a01, a11, false, false);
      auto p2 = __builtin_amdgcn_permlane32_swap(a20, a30, false, false);
      auto p3 = __builtin_amdgcn_permlane32_swap(a21, a31, false, false);
      pb0 = mk8(p0[0], p1[0], p0[1], p1[1]);
      pb1 = mk8(p2[0], p3[0], p2[1], p3[1]);
    }

    const char* vb = (const char*)&Vt[cur][0] + vlane;
    __builtin_amdgcn_s_setprio(1);
    // PV half-0 (kt 0,1) with exp2(st1) woven between MFMAs
#pragma unroll
    for (int ct = 0; ct < 8; ++ct) {
      const bf16x8 v0 = *(const bf16x8*)(vb + ct * 1024);
      const bf16x8 v1 = *(const bf16x8*)(vb + 8192 + ct * 1024);
      acc[ct] = MFMA32(v0, pb0, acc[ct]);
      st1[2 * ct] = fexp2(st1[2 * ct]);
      acc[ct] = MFMA32(v1, pb1, acc[ct]);
      st1[2 * ct + 1] = fexp2(st1[2 * ct + 1]);
    }
    // pack pb2/pb3
    bf16x8 pb2, pb3;
    {
      const uint b00 = pack2(st1[0],  st1[1]),  b01 = pack2(st1[2],  st1[3]);
      const uint b10 = pack2(st1[4],  st1[5]),  b11 = pack2(st1[6],  st1[7]);
      const uint b20 = pack2(st1[8],  st1[9]),  b21 = pack2(st1[10], st1[11]);
      const uint b30 = pack2(st1[12], st1[13]), b31 = pack2(st1[14], st1[15]);
      auto p4 = __builtin_amdgcn_permlane32_swap(b00, b10, false, false);
      auto p5 = __builtin_amdgcn_permlane32_swap(b01, b11, false, false);
      auto p6 = __builtin_amdgcn_permlane32_swap(b20, b30, false, false);
      auto p7 = __builtin_amdgcn_permlane32_swap(b21, b31, false, false);
      pb2 = mk8(p4[0], p5[0], p4[1], p5[1]);
      pb3 = mk8(p6[0], p7[0], p6[1], p7[1]);
    }

    // PV half-1 (kt 2,3) with K-prefetch + st1 row-sum woven between MFMAs.
    // (kf prefetch reads one tile past K range at tt==15 — lands in Vw region
    //  of the same workspace allocation; values unused.)
    float s1 = 0.f;
#pragma unroll
    for (int ct = 0; ct < 8; ++ct) {
      const bf16x8 v2 = *(const bf16x8*)(vb + 16384 + ct * 1024);
      const bf16x8 v3 = *(const bf16x8*)(vb + 24576 + ct * 1024);
      acc[ct] = MFMA32(v2, pb2, acc[ct]);
      if (ct == 0) kf00 = *(const bf16x8*)(kfp + ko00);
      if (ct == 1) kf01 = *(const bf16x8*)(kfp + ko01);
      if (ct == 2) kf10 = *(const bf16x8*)(kfp + ko10);
      if (ct == 3) kf11 = *(const bf16x8*)(kfp + ko11);
      acc[ct] = MFMA32(v3, pb3, acc[ct]);
      s1 += st1[2 * ct] + st1[2 * ct + 1];
    }
    __builtin_amdgcn_s_setprio(0);
    lsum += s0 + s1;

    __syncthreads();   // drains vmcnt (stage done) + all waves done with buf
    cur ^= 1;
    kfp += 64 * DP;    // SALU pointer step
    vsrc += 16384;     // SALU pointer step
  }

  // epilogue: finish row sum, store partials
  lsum += __shfl_xor(lsum, 32, 64);
  const size_t prow = rbase + q0 + qq;
  if (h == 0) pml[prow * 4 + s] = lsum;
  // pacc bf16 [row][s][256]; channel = ct*32 + 8j + 4h + {0..3}
  ushort* pr = pacc + (prow * 4 + s) * 256;
#pragma unroll
  for (int ct = 0; ct < 8; ++ct)
#pragma unroll
    for (int j = 0; j < 4; ++j) {
      uint2 d;
      d.x = pack2(acc[ct][4 * j], acc[ct][4 * j + 1]);
      d.y = pack2(acc[ct][4 * j + 2], acc[ct][4 * j + 3]);
      *(uint2*)&pr[ct * 32 + j * 8 + h * 4] = d;
    }
}

// Combine partials (plain sums — no-max softmax) -> out[...,0:256].
__global__ __launch_bounds__(256) void reduce_o(
    const float* __restrict__ pml, const ushort* __restrict__ pacc,
    float* __restrict__ out) {
  const int t = threadIdx.x;
  const int row = blockIdx.x * 8 + (t >> 5);
  const int c0 = (t & 31) * 8;

  const float L = pml[row * 4] + pml[row * 4 + 1] + pml[row * 4 + 2] + pml[row * 4 + 3];
  float o[8] = {0.f, 0.f, 0.f, 0.f, 0.f, 0.f, 0.f, 0.f};
#pragma unroll
  for (int s = 0; s < 4; ++s) {
    const bf16x8 a = *(const bf16x8*)(pacc + ((size_t)row * 4 + s) * 256 + c0);
#pragma unroll
    for (int i = 0; i < 8; ++i) o[i] += (float)a[i];
  }
  const float inv = 1.f / L;
  float4 o0 = {o[0] * inv, o[1] * inv, o[2] * inv, o[3] * inv};
  float4 o1 = {o[4] * inv, o[5] * inv, o[6] * inv, o[7] * inv};
  float4* op = (float4*)(out + (size_t)row * OUTC + c0);
  op[0] = o0; op[1] = o1;
}

// ===========================================================================
// FALLBACK PATH (round-1, no workspace) — used only if ws_size too small
// ===========================================================================
__global__ __launch_bounds__(256) void proj_fb(
    const float* __restrict__ x, const float* __restrict__ h,
    const float* __restrict__ fw, const float* __restrict__ gw,
    float* __restrict__ out) {
  __shared__ float wl[8192];
  __shared__ float rows[8][260];
  const int t = threadIdx.x;
  const int which = blockIdx.y;
  const float* in = which ? h : x;
  const float* w  = which ? fw : gw;
  for (int i = t; i < 8192; i += 256) wl[i] = w[i];
  const int row0 = blockIdx.x * 32;
  const int d = t & 31, rl = t >> 5;
  for (int rp = 0; rp < 4; ++rp) {
    __syncthreads();
    for (int i = t; i < 2048; i += 256)
      rows[i >> 8][i & 255] = in[(long)(row0 + rp * 8 + (i >> 8)) * CIN + (i & 255)];
    __syncthreads();
    float a = 0.f;
#pragma unroll 8
    for (int c = 0; c < 256; ++c) a = fmaf(rows[rl][c], wl[c * 32 + d], a);
    const long row = row0 + rp * 8 + rl;
    ((ushort*)(out + row * OUTC + 256))[which * 32 + d] = f2bf(a);
  }
}

__global__ __launch_bounds__(256) void attn_fb(
    const float* __restrict__ h, float* __restrict__ out) {
  __shared__ alignas(16) ushort Vt[256][72];
  __shared__ alignas(16) ushort Pl[4][16][72];
  const int t = threadIdx.x;
  const int w = t >> 6, l = t & 63, lo = l & 15, hi = l >> 4;
  const int bid = blockIdx.x;
  const int b = (bid >> 1) & 3;
  const int qb = ((bid >> 3) << 1) | (bid & 1);
  const int q0 = qb * 64;
  const long rowbase = (long)b * NROW;
  const ushort* gslot = (const ushort*)(out + (rowbase + q0 + w * 16 + lo) * OUTC + 256);
  const bf16x8 qf = *(const bf16x8*)(gslot + hi * 8);
  f32x4 acc[16];
#pragma unroll
  for (int i = 0; i < 16; ++i) acc[i] = (f32x4){0.f, 0.f, 0.f, 0.f};
  float mrow[4] = {-1e30f, -1e30f, -1e30f, -1e30f};
  float lsum[4] = {0.f, 0.f, 0.f, 0.f};
  for (int k0 = 0; k0 < NROW; k0 += 64) {
    bf16x8 kf[4];
#pragma unroll
    for (int kt = 0; kt < 4; ++kt) {
      const ushort* fslot =
          (const ushort*)(out + (rowbase + k0 + kt * 16 + lo) * OUTC + 256) + 32;
      kf[kt] = *(const bf16x8*)(fslot + hi * 8);
    }
    __syncthreads();
    {
      const float* hp = h + (rowbase + k0) * CIN + t;
#pragma unroll
      for (int g8 = 0; g8 < 8; ++g8) {
        ushort tmp[8];
#pragma unroll
        for (int i = 0; i < 8; ++i) tmp[i] = f2bf(hp[(g8 * 8 + i) * CIN]);
        *(bf16x8*)&Vt[t][g8 * 8] = *(const bf16x8*)tmp;
      }
    }
    __syncthreads();
    f32x4 sv[4];
#pragma unroll
    for (int kt = 0; kt < 4; ++kt)
      sv[kt] = __builtin_amdgcn_mfma_f32_16x16x32_bf16(
          qf, kf[kt], (f32x4){0.f, 0.f, 0.f, 0.f}, 0, 0, 0);
    float alpha[4];
    bool upd = false;
#pragma unroll
    for (int r = 0; r < 4; ++r) {
      float m4 = fmaxf(fmaxf(sv[0][r], sv[1][r]), fmaxf(sv[2][r], sv[3][r]));
#pragma unroll
      for (int off = 1; off < 16; off <<= 1) m4 = fmaxf(m4, __shfl_xor(m4, off, 64));
      const float mn = fmaxf(mrow[r], m4);
      alpha[r] = __expf(mrow[r] - mn);
      upd |= (mn > mrow[r]);
      mrow[r] = mn;
    }
    if (__any(upd)) {
#pragma unroll
      for (int ct = 0; ct < 16; ++ct)
#pragma unroll
        for (int r = 0; r < 4; ++r) acc[ct][r] *= alpha[r];
#pragma unroll
      for (int r = 0; r < 4; ++r) lsum[r] *= alpha[r];
    }
#pragma unroll
    for (int r = 0; r < 4; ++r) {
      float ps = 0.f;
#pragma unroll
      for (int kt = 0; kt < 4; ++kt) {
        const float p = __expf(sv[kt][r] - mrow[r]);
        sv[kt][r] = p;
        ps += p;
      }
#pragma unroll
      for (int off = 1; off < 16; off <<= 1) ps += __shfl_xor(ps, off, 64);
      lsum[r] += ps;
    }
#pragma unroll
    for (int kt = 0; kt < 4; ++kt)
#pragma unroll
      for (int r = 0; r < 4; ++r)
        Pl[w][hi * 4 + r][kt * 16 + lo] = f2bf(sv[kt][r]);
    asm volatile("s_waitcnt lgkmcnt(0)" ::: "memory");
    const bf16x8 pa0 = *(const bf16x8*)&Pl[w][lo][hi * 8];
    const bf16x8 pa1 = *(const bf16x8*)&Pl[w][lo][32 + hi * 8];
#pragma unroll
    for (int ct = 0; ct < 16; ++ct) {
      const bf16x8 v0 = *(const bf16x8*)&Vt[ct * 16 + lo][hi * 8];
      const bf16x8 v1 = *(const bf16x8*)&Vt[ct * 16 + lo][32 + hi * 8];
      acc[ct] = __builtin_amdgcn_mfma_f32_16x16x32_bf16(pa0, v0, acc[ct], 0, 0, 0);
      acc[ct] = __builtin_amdgcn_mfma_f32_16x16x32_bf16(pa1, v1, acc[ct], 0, 0, 0);
    }
  }
#pragma unroll
  for (int r = 0; r < 4; ++r) {
    const float inv = 1.f / lsum[r];
    float* orow = out + (rowbase + q0 + w * 16 + hi * 4 + r) * OUTC;
#pragma unroll
    for (int ct = 0; ct < 16; ++ct) orow[ct * 16 + lo] = acc[ct][r] * inv;
  }
}

__global__ __launch_bounds__(256) void concat_fb(
    const float4* __restrict__ x, float4* __restrict__ out) {
  const int idx = blockIdx.x * 256 + threadIdx.x;
  const int row = idx >> 6, c4 = idx & 63;
  out[row * 128 + 64 + c4] = x[idx];
}

// ===========================================================================
extern "C" void kernel_launch(void* const* d_in, const int* in_sizes, int n_in,
                              void* d_out, int out_size, void* d_ws, size_t ws_size,
                              hipStream_t stream) {
  const float* x  = (const float*)d_in[0];
  const float* h  = (const float*)d_in[1];
  const float* fw = (const float*)d_in[2];
  const float* gw = (const float*)d_in[3];
  float* out = (float*)d_out;

  const size_t rows = (size_t)NB * NROW;                      // 16384
  const size_t base = 10ull * 1024 * 1024;                    // Q(1)+K(1)+V(8)
  const size_t need = base + rows * 4 * 8 + rows * 4 * 512;   // pml + pacc

  if (ws_size >= need) {
    ushort* Qw = (ushort*)d_ws;
    ushort* Kw = Qw + (1ull << 19);            // +1MB
    ushort* Vw = Kw + (1ull << 19);            // +1MB (V: 8MB)
    float*  pml  = (float*)((char*)d_ws + base);
    ushort* pacc = (ushort*)((char*)d_ws + base + rows * 4 * 8);

    proj_mfma<<<dim3(256, 2), 256, 0, stream>>>(x, h, fw, gw, Qw, Kw, Vw, out);
    attn32f<<<512, 256, 0, stream>>>(Qw, Kw, Vw, pml, pacc);
    reduce_o<<<2048, 256, 0, stream>>>(pml, pacc, out);
  } else {
    proj_fb<<<dim3(512, 2), 256, 0, stream>>>(x, h, fw, gw, out);
    attn_fb<<<256, 256, 0, stream>>>(h, out);
    concat_fb<<<4096, 256, 0, stream>>>((const float4*)x, (float4*)out);
  }
}